// Round 1
// baseline (245.087 us; speedup 1.0000x reference)
//
#include <hip/hip_runtime.h>
#include <stdint.h>

#define T_SEQ 2048
#define CDIM 1024
#define NHEAD 16
#define HS 64

typedef __bf16 bf16x8 __attribute__((ext_vector_type(8)));
typedef float f32x4 __attribute__((ext_vector_type(4)));

__device__ __forceinline__ unsigned short f2bf(float f) {
  union { float f; unsigned u; } c; c.f = f;
  unsigned r = c.u + 0x7FFFu + ((c.u >> 16) & 1u);
  return (unsigned short)(r >> 16);
}

__device__ __forceinline__ void gload_lds16(const void* g, void* l) {
  __builtin_amdgcn_global_load_lds((__attribute__((address_space(1))) void*)(g),
                                   (__attribute__((address_space(3))) void*)(l),
                                   16, 0, 0);
}

// x fp32 [4096][1024] -> bf16 same layout. 4 elems/thread.
__global__ __launch_bounds__(256) void k_cvt_x(const float* __restrict__ x,
                                               unsigned short* __restrict__ xb) {
  int i = blockIdx.x * 256 + threadIdx.x;
  float4 f = reinterpret_cast<const float4*>(x)[i];
  ushort4 u;
  u.x = f2bf(f.x); u.y = f2bf(f.y); u.z = f2bf(f.z); u.w = f2bf(f.w);
  reinterpret_cast<ushort4*>(xb)[i] = u;
}

// W [K][N] fp32 -> Wt [N][K] bf16 (tiled transpose)
__global__ __launch_bounds__(256) void k_transpose(const float* __restrict__ W,
                                                   unsigned short* __restrict__ Wt,
                                                   int K, int N) {
  __shared__ float tile[32][33];
  int n0 = blockIdx.x * 32, k0 = blockIdx.y * 32;
  int c = threadIdx.x & 31, r0 = threadIdx.x >> 5;
#pragma unroll
  for (int r = r0; r < 32; r += 8) tile[r][c] = W[(size_t)(k0 + r) * N + n0 + c];
  __syncthreads();
#pragma unroll
  for (int r = r0; r < 32; r += 8) Wt[(size_t)(n0 + r) * K + k0 + c] = f2bf(tile[c][r]);
}

// C = A[M][KD] * Bt[N][KD]^T + bias. 128x128 tile, 4 waves, BK=32.
// MODE 0: qkv scatter epilogue (bf16). MODE 1: fp32 out.
template <int MODE, int KD>
__global__ __launch_bounds__(256) void k_gemm(const unsigned short* __restrict__ A,
                                              const unsigned short* __restrict__ Bt,
                                              const float* __restrict__ bias,
                                              float* __restrict__ outF,
                                              unsigned short* __restrict__ qb,
                                              unsigned short* __restrict__ kb,
                                              unsigned short* __restrict__ vb) {
  __shared__ __align__(16) unsigned short Al[128 * 32];
  __shared__ __align__(16) unsigned short Bl[128 * 32];
  const int tid = threadIdx.x;
  const int wave = tid >> 6, lane = tid & 63;
  const int m0 = blockIdx.x * 128, n0 = blockIdx.y * 128;
  const int wr = (wave >> 1) * 64, wc = (wave & 1) * 64;
  const int srow = tid >> 2, scol = (tid & 3) * 8;
  const int ka = (lane >> 4) * 8;
  f32x4 acc[4][4];
#pragma unroll
  for (int m = 0; m < 4; ++m)
#pragma unroll
    for (int n = 0; n < 4; ++n) acc[m][n] = f32x4{0.f, 0.f, 0.f, 0.f};

  for (int k0 = 0; k0 < KD; k0 += 32) {
#pragma unroll
    for (int r = 0; r < 2; ++r) {
      gload_lds16(A + (size_t)(m0 + r * 64 + srow) * KD + k0 + scol,
                  (char*)Al + r * 4096 + wave * 1024);
      gload_lds16(Bt + (size_t)(n0 + r * 64 + srow) * KD + k0 + scol,
                  (char*)Bl + r * 4096 + wave * 1024);
    }
    __syncthreads();
    bf16x8 af[4], bfr[4];
#pragma unroll
    for (int m = 0; m < 4; ++m)
      af[m] = *(const bf16x8*)&Al[(wr + m * 16 + (lane & 15)) * 32 + ka];
#pragma unroll
    for (int n = 0; n < 4; ++n)
      bfr[n] = *(const bf16x8*)&Bl[(wc + n * 16 + (lane & 15)) * 32 + ka];
#pragma unroll
    for (int m = 0; m < 4; ++m)
#pragma unroll
      for (int n = 0; n < 4; ++n)
        acc[m][n] = __builtin_amdgcn_mfma_f32_16x16x32_bf16(af[m], bfr[n], acc[m][n], 0, 0, 0);
    __syncthreads();
  }

#pragma unroll
  for (int m = 0; m < 4; ++m)
#pragma unroll
    for (int n = 0; n < 4; ++n)
#pragma unroll
      for (int j = 0; j < 4; ++j) {
        int row = m0 + wr + m * 16 + (lane >> 4) * 4 + j;
        int col = n0 + wc + n * 16 + (lane & 15);
        float v = acc[m][n][j] + bias[col];
        if (MODE == 1) {
          outF[(size_t)row * CDIM + col] = v;
        } else {
          int which = col >> 10;
          int h = (col >> 6) & 15;
          int d = col & 63;
          int b = row >> 11, t = row & (T_SEQ - 1);
          int bh = b * NHEAD + h;
          unsigned short bv = f2bf(v);
          if (which == 0)      qb[((size_t)bh * T_SEQ + t) * HS + d] = bv;
          else if (which == 1) kb[((size_t)bh * T_SEQ + t) * HS + d] = bv;
          else                 vb[((size_t)bh * HS + d) * T_SEQ + t] = bv;
        }
      }
}

// Flash attention: 4 waves x 32 q-rows = 128-row Q tile, KV tiles of 64.
// q,k: [bh][t][64] bf16; v: [bh][64][t] bf16 (transposed); y: [4096][1024] bf16.
__global__ __launch_bounds__(256) void k_attn(const unsigned short* __restrict__ qb,
                                              const unsigned short* __restrict__ kb,
                                              const unsigned short* __restrict__ vb,
                                              unsigned short* __restrict__ yb) {
  __shared__ __align__(16) unsigned short Kl[64 * 64];
  __shared__ __align__(16) unsigned short Vl[64 * 64];
  __shared__ __align__(16) unsigned short Pl[128 * 64];
  const int qt = (int)gridDim.x - 1 - (int)blockIdx.x;  // heavy tiles first
  const int bh = blockIdx.y;
  const int q0 = qt * 128;
  const int tid = threadIdx.x, wave = tid >> 6, lane = tid & 63;
  const unsigned short* qh = qb + (size_t)bh * T_SEQ * HS;
  const unsigned short* kh = kb + (size_t)bh * T_SEQ * HS;
  const unsigned short* vh = vb + (size_t)bh * HS * T_SEQ;

  bf16x8 qf[2][2];
#pragma unroll
  for (int m = 0; m < 2; ++m)
#pragma unroll
    for (int kk = 0; kk < 2; ++kk)
      qf[m][kk] = *(const bf16x8*)&qh[(size_t)(q0 + wave * 32 + m * 16 + (lane & 15)) * HS +
                                      kk * 32 + (lane >> 4) * 8];
  f32x4 o[2][4];
  float Mx[2][4], Ls[2][4];
#pragma unroll
  for (int m = 0; m < 2; ++m) {
#pragma unroll
    for (int n = 0; n < 4; ++n) o[m][n] = f32x4{0.f, 0.f, 0.f, 0.f};
#pragma unroll
    for (int j = 0; j < 4; ++j) { Mx[m][j] = -INFINITY; Ls[m][j] = 0.f; }
  }

  const int nkt = 2 * qt + 2;
  for (int kt = 0; kt < nkt; ++kt) {
    __syncthreads();
#pragma unroll
    for (int r = 0; r < 2; ++r) {
      int e = r * 2048 + tid * 8;
      int row = e >> 6, col = e & 63;
      gload_lds16(kh + (size_t)(kt * 64 + row) * HS + col, (char*)Kl + r * 4096 + wave * 1024);
      gload_lds16(vh + (size_t)row * T_SEQ + kt * 64 + col, (char*)Vl + r * 4096 + wave * 1024);
    }
    __syncthreads();

    bf16x8 kf[4][2];
#pragma unroll
    for (int n = 0; n < 4; ++n)
#pragma unroll
      for (int kk = 0; kk < 2; ++kk)
        kf[n][kk] = *(const bf16x8*)&Kl[(n * 16 + (lane & 15)) * 64 + kk * 32 + (lane >> 4) * 8];

    f32x4 s[2][4];
#pragma unroll
    for (int m = 0; m < 2; ++m)
#pragma unroll
      for (int n = 0; n < 4; ++n) {
        f32x4 z = f32x4{0.f, 0.f, 0.f, 0.f};
        z = __builtin_amdgcn_mfma_f32_16x16x32_bf16(qf[m][0], kf[n][0], z, 0, 0, 0);
        z = __builtin_amdgcn_mfma_f32_16x16x32_bf16(qf[m][1], kf[n][1], z, 0, 0, 0);
        s[m][n] = z;
      }

    const bool diag = (kt * 64 + 63 > q0);
#pragma unroll
    for (int m = 0; m < 2; ++m)
#pragma unroll
      for (int j = 0; j < 4; ++j) {
        const int qg = q0 + wave * 32 + m * 16 + (lane >> 4) * 4 + j;
        float sv[4];
        float mx = -3.0e38f;
#pragma unroll
        for (int n = 0; n < 4; ++n) {
          float v = s[m][n][j] * 0.125f;  // 1/sqrt(64)
          if (diag && (kt * 64 + n * 16 + (lane & 15) > qg)) v = -3.0e38f;
          sv[n] = v;
          mx = fmaxf(mx, v);
        }
        mx = fmaxf(mx, __shfl_xor(mx, 1));
        mx = fmaxf(mx, __shfl_xor(mx, 2));
        mx = fmaxf(mx, __shfl_xor(mx, 4));
        mx = fmaxf(mx, __shfl_xor(mx, 8));
        const float newM = fmaxf(Mx[m][j], mx);
        const float alpha = __expf(Mx[m][j] - newM);
        float rs = 0.f;
#pragma unroll
        for (int n = 0; n < 4; ++n) {
          float p = __expf(sv[n] - newM);
          rs += p;
          Pl[(wave * 32 + m * 16 + (lane >> 4) * 4 + j) * 64 + n * 16 + (lane & 15)] = f2bf(p);
        }
        rs += __shfl_xor(rs, 1);
        rs += __shfl_xor(rs, 2);
        rs += __shfl_xor(rs, 4);
        rs += __shfl_xor(rs, 8);
        Ls[m][j] = Ls[m][j] * alpha + rs;
        Mx[m][j] = newM;
#pragma unroll
        for (int n = 0; n < 4; ++n) o[m][n][j] *= alpha;
      }

    // PV: o += P * V  (A = P rows from wave-private LDS, B = V^T rows)
#pragma unroll
    for (int kk = 0; kk < 2; ++kk) {
      bf16x8 vf[4];
#pragma unroll
      for (int n = 0; n < 4; ++n)
        vf[n] = *(const bf16x8*)&Vl[((lane & 15) + n * 16) * 64 + kk * 32 + (lane >> 4) * 8];
#pragma unroll
      for (int m = 0; m < 2; ++m) {
        bf16x8 pf = *(const bf16x8*)&Pl[(wave * 32 + m * 16 + (lane & 15)) * 64 +
                                        kk * 32 + (lane >> 4) * 8];
#pragma unroll
        for (int n = 0; n < 4; ++n)
          o[m][n] = __builtin_amdgcn_mfma_f32_16x16x32_bf16(pf, vf[n], o[m][n], 0, 0, 0);
      }
    }
  }

  const int b = bh >> 4, h = bh & 15;
#pragma unroll
  for (int m = 0; m < 2; ++m)
#pragma unroll
    for (int j = 0; j < 4; ++j) {
      const float inv = 1.0f / Ls[m][j];
      const int tg = b * T_SEQ + q0 + wave * 32 + m * 16 + (lane >> 4) * 4 + j;
#pragma unroll
      for (int n = 0; n < 4; ++n)
        yb[(size_t)tg * CDIM + h * 64 + n * 16 + (lane & 15)] = f2bf(o[m][n][j] * inv);
    }
}

extern "C" void kernel_launch(void* const* d_in, const int* in_sizes, int n_in,
                              void* d_out, int out_size, void* d_ws, size_t ws_size,
                              hipStream_t stream) {
  (void)in_sizes; (void)n_in; (void)out_size; (void)ws_size;
  const float* x      = (const float*)d_in[0];
  const float* W_attn = (const float*)d_in[1];
  const float* b_attn = (const float*)d_in[2];
  const float* W_proj = (const float*)d_in[3];
  const float* b_proj = (const float*)d_in[4];
  float* out = (float*)d_out;
  char* ws = (char*)d_ws;

  unsigned short* xb  = (unsigned short*)(ws);              //  8 MiB [4096][1024]
  unsigned short* Wta = (unsigned short*)(ws + 8388608);    //  6 MiB [3072][1024]
  unsigned short* Wtp = (unsigned short*)(ws + 14680064);   //  2 MiB [1024][1024]
  unsigned short* qbf = (unsigned short*)(ws + 16777216);   //  8 MiB [32][2048][64]
  unsigned short* kbf = (unsigned short*)(ws + 25165824);   //  8 MiB [32][2048][64]
  unsigned short* vbf = (unsigned short*)(ws + 33554432);   //  8 MiB [32][64][2048]
  unsigned short* ybf = (unsigned short*)(ws + 41943040);   //  8 MiB [4096][1024]

  k_cvt_x<<<4096, 256, 0, stream>>>(x, xb);
  k_transpose<<<dim3(96, 32), 256, 0, stream>>>(W_attn, Wta, 1024, 3072);
  k_transpose<<<dim3(32, 32), 256, 0, stream>>>(W_proj, Wtp, 1024, 1024);
  k_gemm<0, 1024><<<dim3(32, 24), 256, 0, stream>>>(xb, Wta, b_attn, nullptr, qbf, kbf, vbf);
  k_attn<<<dim3(16, 32), 256, 0, stream>>>(qbf, kbf, vbf, ybf);
  k_gemm<1, 1024><<<dim3(32, 8), 256, 0, stream>>>(ybf, Wtp, b_proj, out, nullptr, nullptr, nullptr);
}

// Round 2
// 197.515 us; speedup vs baseline: 1.2409x; 1.2409x over previous
//
#include <hip/hip_runtime.h>
#include <stdint.h>

#define T_SEQ 2048
#define CDIM 1024
#define NHEAD 16
#define HS 64

typedef __bf16 bf16x8 __attribute__((ext_vector_type(8)));
typedef float f32x4 __attribute__((ext_vector_type(4)));

__device__ __forceinline__ unsigned short f2bf(float f) {
  union { float f; unsigned u; } c; c.f = f;
  unsigned r = c.u + 0x7FFFu + ((c.u >> 16) & 1u);
  return (unsigned short)(r >> 16);
}

__device__ __forceinline__ void gload_lds16(const void* g, void* l) {
  __builtin_amdgcn_global_load_lds((__attribute__((address_space(1))) void*)(g),
                                   (__attribute__((address_space(3))) void*)(l),
                                   16, 0, 0);
}

// x fp32 [4096][1024] -> bf16 same layout. 4 elems/thread.
__global__ __launch_bounds__(256) void k_cvt_x(const float* __restrict__ x,
                                               unsigned short* __restrict__ xb) {
  int i = blockIdx.x * 256 + threadIdx.x;
  float4 f = reinterpret_cast<const float4*>(x)[i];
  ushort4 u;
  u.x = f2bf(f.x); u.y = f2bf(f.y); u.z = f2bf(f.z); u.w = f2bf(f.w);
  reinterpret_cast<ushort4*>(xb)[i] = u;
}

// W [K][N] fp32 -> Wt [N][K] bf16 (tiled transpose)
__global__ __launch_bounds__(256) void k_transpose(const float* __restrict__ W,
                                                   unsigned short* __restrict__ Wt,
                                                   int K, int N) {
  __shared__ float tile[32][33];
  int n0 = blockIdx.x * 32, k0 = blockIdx.y * 32;
  int c = threadIdx.x & 31, r0 = threadIdx.x >> 5;
#pragma unroll
  for (int r = r0; r < 32; r += 8) tile[r][c] = W[(size_t)(k0 + r) * N + n0 + c];
  __syncthreads();
#pragma unroll
  for (int r = r0; r < 32; r += 8) Wt[(size_t)(n0 + r) * K + k0 + c] = f2bf(tile[c][r]);
}

// C = A[M][KD] * Bt[N][KD]^T + bias. 128x128 tile, 4 waves, BK=32.
// MODE 0: qkv scatter epilogue (bf16). MODE 1: fp32 out.
template <int MODE, int KD>
__global__ __launch_bounds__(256) void k_gemm(const unsigned short* __restrict__ A,
                                              const unsigned short* __restrict__ Bt,
                                              const float* __restrict__ bias,
                                              float* __restrict__ outF,
                                              unsigned short* __restrict__ qb,
                                              unsigned short* __restrict__ kb,
                                              unsigned short* __restrict__ vb) {
  __shared__ __align__(16) unsigned short Al[128 * 32];
  __shared__ __align__(16) unsigned short Bl[128 * 32];
  const int tid = threadIdx.x;
  const int wave = tid >> 6, lane = tid & 63;
  const int m0 = blockIdx.x * 128, n0 = blockIdx.y * 128;
  const int wr = (wave >> 1) * 64, wc = (wave & 1) * 64;
  const int srow = tid >> 2, scol = (tid & 3) * 8;
  const int ka = (lane >> 4) * 8;
  f32x4 acc[4][4];
#pragma unroll
  for (int m = 0; m < 4; ++m)
#pragma unroll
    for (int n = 0; n < 4; ++n) acc[m][n] = f32x4{0.f, 0.f, 0.f, 0.f};

  for (int k0 = 0; k0 < KD; k0 += 32) {
#pragma unroll
    for (int r = 0; r < 2; ++r) {
      gload_lds16(A + (size_t)(m0 + r * 64 + srow) * KD + k0 + scol,
                  (char*)Al + r * 4096 + wave * 1024);
      gload_lds16(Bt + (size_t)(n0 + r * 64 + srow) * KD + k0 + scol,
                  (char*)Bl + r * 4096 + wave * 1024);
    }
    __syncthreads();
    bf16x8 af[4], bfr[4];
#pragma unroll
    for (int m = 0; m < 4; ++m)
      af[m] = *(const bf16x8*)&Al[(wr + m * 16 + (lane & 15)) * 32 + ka];
#pragma unroll
    for (int n = 0; n < 4; ++n)
      bfr[n] = *(const bf16x8*)&Bl[(wc + n * 16 + (lane & 15)) * 32 + ka];
#pragma unroll
    for (int m = 0; m < 4; ++m)
#pragma unroll
      for (int n = 0; n < 4; ++n)
        acc[m][n] = __builtin_amdgcn_mfma_f32_16x16x32_bf16(af[m], bfr[n], acc[m][n], 0, 0, 0);
    __syncthreads();
  }

#pragma unroll
  for (int m = 0; m < 4; ++m)
#pragma unroll
    for (int n = 0; n < 4; ++n)
#pragma unroll
      for (int j = 0; j < 4; ++j) {
        int row = m0 + wr + m * 16 + (lane >> 4) * 4 + j;
        int col = n0 + wc + n * 16 + (lane & 15);
        float v = acc[m][n][j] + bias[col];
        if (MODE == 1) {
          outF[(size_t)row * CDIM + col] = v;
        } else {
          int which = col >> 10;
          int h = (col >> 6) & 15;
          int d = col & 63;
          int b = row >> 11, t = row & (T_SEQ - 1);
          int bh = b * NHEAD + h;
          unsigned short bv = f2bf(v);
          if (which == 0)      qb[((size_t)bh * T_SEQ + t) * HS + d] = bv;
          else if (which == 1) kb[((size_t)bh * T_SEQ + t) * HS + d] = bv;
          else                 vb[((size_t)bh * HS + d) * T_SEQ + t] = bv;
        }
      }
}

// Barrier-free flash attention. Each wave independently owns 32 q-rows.
// K,V fragments read directly from global (L2-resident per XCD after remap).
// Only P goes through wave-private padded LDS (stride 72 elems -> no conflicts).
// q,k: [bh][t][64] bf16; v: [bh][64][t] bf16 (transposed); y: [4096][1024] bf16.
#define PSTR 72
__global__ __launch_bounds__(256) void k_attn(const unsigned short* __restrict__ qb,
                                              const unsigned short* __restrict__ kb,
                                              const unsigned short* __restrict__ vb,
                                              unsigned short* __restrict__ yb) {
  __shared__ __align__(16) unsigned short Pl[4 * 32 * PSTR];
  // XCD-aware remap: assume xcd = linear_id & 7. Give each XCD 4 bh values so
  // its 4 MiB L2 holds their K/V (4 x 768 KiB). Heavy q-tiles first within XCD.
  const int rid = blockIdx.x;
  const int xcd = rid & 7, s = rid >> 3;       // s in 0..63
  const int bh = xcd * 4 + (s & 3);
  const int qt = 15 - (s >> 2);
  const int tid = threadIdx.x, wave = tid >> 6, lane = tid & 63;
  const int l15 = lane & 15, lh = lane >> 4;
  const int q0w = qt * 128 + wave * 32;        // this wave's 32 q-rows
  const unsigned short* qh = qb + (size_t)bh * T_SEQ * HS;
  const unsigned short* kh = kb + (size_t)bh * T_SEQ * HS;
  const unsigned short* vh = vb + (size_t)bh * HS * T_SEQ;
  unsigned short* Pw = &Pl[wave * 32 * PSTR];

  bf16x8 qf[2][2];
#pragma unroll
  for (int m = 0; m < 2; ++m)
#pragma unroll
    for (int kk = 0; kk < 2; ++kk)
      qf[m][kk] = *(const bf16x8*)&qh[(size_t)(q0w + m * 16 + l15) * HS + kk * 32 + lh * 8];

  f32x4 o[2][4];
  float Mx[2][4], Ls[2][4];
#pragma unroll
  for (int m = 0; m < 2; ++m) {
#pragma unroll
    for (int n = 0; n < 4; ++n) o[m][n] = f32x4{0.f, 0.f, 0.f, 0.f};
#pragma unroll
    for (int j = 0; j < 4; ++j) { Mx[m][j] = -INFINITY; Ls[m][j] = 0.f; }
  }

  const float SC = 0.125f * 1.44269504f;  // 1/sqrt(64) * log2(e)
  const int nkt = (q0w >> 6) + 1;
  for (int kt = 0; kt < nkt; ++kt) {
    const int kvb = kt * 64;
    bf16x8 kf[4][2], vf[4][2];
#pragma unroll
    for (int n = 0; n < 4; ++n)
#pragma unroll
      for (int kk = 0; kk < 2; ++kk) {
        kf[n][kk] = *(const bf16x8*)&kh[(size_t)(kvb + n * 16 + l15) * HS + kk * 32 + lh * 8];
        vf[n][kk] = *(const bf16x8*)&vh[(size_t)(n * 16 + l15) * T_SEQ + kvb + kk * 32 + lh * 8];
      }

    f32x4 s2[2][4];
#pragma unroll
    for (int m = 0; m < 2; ++m)
#pragma unroll
      for (int n = 0; n < 4; ++n) {
        f32x4 z = f32x4{0.f, 0.f, 0.f, 0.f};
        z = __builtin_amdgcn_mfma_f32_16x16x32_bf16(qf[m][0], kf[n][0], z, 0, 0, 0);
        z = __builtin_amdgcn_mfma_f32_16x16x32_bf16(qf[m][1], kf[n][1], z, 0, 0, 0);
        s2[m][n] = z;
      }

    const bool diag = (kvb + 63 > q0w);
#pragma unroll
    for (int m = 0; m < 2; ++m)
#pragma unroll
      for (int j = 0; j < 4; ++j) {
        const int qg = q0w + m * 16 + lh * 4 + j;
        float sv[4];
        float mx = -3.0e38f;
#pragma unroll
        for (int n = 0; n < 4; ++n) {
          float v = s2[m][n][j] * SC;  // log2-domain scores
          if (diag && (kvb + n * 16 + l15 > qg)) v = -3.0e38f;
          sv[n] = v;
          mx = fmaxf(mx, v);
        }
        mx = fmaxf(mx, __shfl_xor(mx, 1));
        mx = fmaxf(mx, __shfl_xor(mx, 2));
        mx = fmaxf(mx, __shfl_xor(mx, 4));
        mx = fmaxf(mx, __shfl_xor(mx, 8));
        const float newM = fmaxf(Mx[m][j], mx);
        const float alpha = __builtin_exp2f(Mx[m][j] - newM);
        float rs = 0.f;
#pragma unroll
        for (int n = 0; n < 4; ++n) {
          float p = __builtin_exp2f(sv[n] - newM);
          rs += p;
          Pw[(m * 16 + lh * 4 + j) * PSTR + n * 16 + l15] = f2bf(p);
        }
        rs += __shfl_xor(rs, 1);
        rs += __shfl_xor(rs, 2);
        rs += __shfl_xor(rs, 4);
        rs += __shfl_xor(rs, 8);
        Ls[m][j] = Ls[m][j] * alpha + rs;
        Mx[m][j] = newM;
#pragma unroll
        for (int n = 0; n < 4; ++n) o[m][n][j] *= alpha;
      }

    __builtin_amdgcn_wave_barrier();  // keep ds_writes above the reads below

    bf16x8 pf[2][2];
#pragma unroll
    for (int m = 0; m < 2; ++m)
#pragma unroll
      for (int kk = 0; kk < 2; ++kk)
        pf[m][kk] = *(const bf16x8*)&Pw[(m * 16 + l15) * PSTR + kk * 32 + lh * 8];

#pragma unroll
    for (int m = 0; m < 2; ++m)
#pragma unroll
      for (int n = 0; n < 4; ++n) {
        o[m][n] = __builtin_amdgcn_mfma_f32_16x16x32_bf16(pf[m][0], vf[n][0], o[m][n], 0, 0, 0);
        o[m][n] = __builtin_amdgcn_mfma_f32_16x16x32_bf16(pf[m][1], vf[n][1], o[m][n], 0, 0, 0);
      }
  }

  const int b = bh >> 4, h = bh & 15;
#pragma unroll
  for (int m = 0; m < 2; ++m)
#pragma unroll
    for (int j = 0; j < 4; ++j) {
      const float inv = 1.0f / Ls[m][j];
      const int tg = b * T_SEQ + q0w + m * 16 + lh * 4 + j;
#pragma unroll
      for (int n = 0; n < 4; ++n)
        yb[(size_t)tg * CDIM + h * 64 + n * 16 + l15] = f2bf(o[m][n][j] * inv);
    }
}

extern "C" void kernel_launch(void* const* d_in, const int* in_sizes, int n_in,
                              void* d_out, int out_size, void* d_ws, size_t ws_size,
                              hipStream_t stream) {
  (void)in_sizes; (void)n_in; (void)out_size; (void)ws_size;
  const float* x      = (const float*)d_in[0];
  const float* W_attn = (const float*)d_in[1];
  const float* b_attn = (const float*)d_in[2];
  const float* W_proj = (const float*)d_in[3];
  const float* b_proj = (const float*)d_in[4];
  float* out = (float*)d_out;
  char* ws = (char*)d_ws;

  unsigned short* xb  = (unsigned short*)(ws);              //  8 MiB [4096][1024]
  unsigned short* Wta = (unsigned short*)(ws + 8388608);    //  6 MiB [3072][1024]
  unsigned short* Wtp = (unsigned short*)(ws + 14680064);   //  2 MiB [1024][1024]
  unsigned short* qbf = (unsigned short*)(ws + 16777216);   //  8 MiB [32][2048][64]
  unsigned short* kbf = (unsigned short*)(ws + 25165824);   //  8 MiB [32][2048][64]
  unsigned short* vbf = (unsigned short*)(ws + 33554432);   //  8 MiB [32][64][2048]
  unsigned short* ybf = (unsigned short*)(ws + 41943040);   //  8 MiB [4096][1024]

  k_cvt_x<<<4096, 256, 0, stream>>>(x, xb);
  k_transpose<<<dim3(96, 32), 256, 0, stream>>>(W_attn, Wta, 1024, 3072);
  k_transpose<<<dim3(32, 32), 256, 0, stream>>>(W_proj, Wtp, 1024, 1024);
  k_gemm<0, 1024><<<dim3(32, 24), 256, 0, stream>>>(xb, Wta, b_attn, nullptr, qbf, kbf, vbf);
  k_attn<<<512, 256, 0, stream>>>(qbf, kbf, vbf, ybf);
  k_gemm<1, 1024><<<dim3(32, 8), 256, 0, stream>>>(ybf, Wtp, b_proj, out, nullptr, nullptr, nullptr);
}

// Round 3
// 195.904 us; speedup vs baseline: 1.2511x; 1.0082x over previous
//
#include <hip/hip_runtime.h>
#include <stdint.h>

#define T_SEQ 2048
#define CDIM 1024
#define NHEAD 16
#define HS 64

typedef __bf16 bf16x8 __attribute__((ext_vector_type(8)));
typedef float f32x4 __attribute__((ext_vector_type(4)));

__device__ __forceinline__ unsigned short f2bf(float f) {
  union { float f; unsigned u; } c; c.f = f;
  unsigned r = c.u + 0x7FFFu + ((c.u >> 16) & 1u);
  return (unsigned short)(r >> 16);
}

__device__ __forceinline__ void gload_lds16(const void* g, void* l) {
  __builtin_amdgcn_global_load_lds((__attribute__((address_space(1))) void*)(g),
                                   (__attribute__((address_space(3))) void*)(l),
                                   16, 0, 0);
}

// x fp32 [4096][1024] -> bf16 same layout. 4 elems/thread.
__global__ __launch_bounds__(256) void k_cvt_x(const float* __restrict__ x,
                                               unsigned short* __restrict__ xb) {
  int i = blockIdx.x * 256 + threadIdx.x;
  float4 f = reinterpret_cast<const float4*>(x)[i];
  ushort4 u;
  u.x = f2bf(f.x); u.y = f2bf(f.y); u.z = f2bf(f.z); u.w = f2bf(f.w);
  reinterpret_cast<ushort4*>(xb)[i] = u;
}

// W [K][N] fp32 -> Wt [N][K] bf16 (tiled transpose)
__global__ __launch_bounds__(256) void k_transpose(const float* __restrict__ W,
                                                   unsigned short* __restrict__ Wt,
                                                   int K, int N) {
  __shared__ float tile[32][33];
  int n0 = blockIdx.x * 32, k0 = blockIdx.y * 32;
  int c = threadIdx.x & 31, r0 = threadIdx.x >> 5;
#pragma unroll
  for (int r = r0; r < 32; r += 8) tile[r][c] = W[(size_t)(k0 + r) * N + n0 + c];
  __syncthreads();
#pragma unroll
  for (int r = r0; r < 32; r += 8) Wt[(size_t)(n0 + r) * K + k0 + c] = f2bf(tile[c][r]);
}

// C = A[M][KD] * Bt[N][KD]^T + bias. 128x128 tile, 4 waves, BK=32.
// MODE 0: qkv scatter epilogue (bf16). MODE 1: fp32 out.
template <int MODE, int KD>
__global__ __launch_bounds__(256) void k_gemm(const unsigned short* __restrict__ A,
                                              const unsigned short* __restrict__ Bt,
                                              const float* __restrict__ bias,
                                              float* __restrict__ outF,
                                              unsigned short* __restrict__ qb,
                                              unsigned short* __restrict__ kb,
                                              unsigned short* __restrict__ vb) {
  __shared__ __align__(16) unsigned short Al[128 * 32];
  __shared__ __align__(16) unsigned short Bl[128 * 32];
  const int tid = threadIdx.x;
  const int wave = tid >> 6, lane = tid & 63;
  const int m0 = blockIdx.x * 128, n0 = blockIdx.y * 128;
  const int wr = (wave >> 1) * 64, wc = (wave & 1) * 64;
  const int srow = tid >> 2, scol = (tid & 3) * 8;
  const int ka = (lane >> 4) * 8;
  f32x4 acc[4][4];
#pragma unroll
  for (int m = 0; m < 4; ++m)
#pragma unroll
    for (int n = 0; n < 4; ++n) acc[m][n] = f32x4{0.f, 0.f, 0.f, 0.f};

  for (int k0 = 0; k0 < KD; k0 += 32) {
#pragma unroll
    for (int r = 0; r < 2; ++r) {
      gload_lds16(A + (size_t)(m0 + r * 64 + srow) * KD + k0 + scol,
                  (char*)Al + r * 4096 + wave * 1024);
      gload_lds16(Bt + (size_t)(n0 + r * 64 + srow) * KD + k0 + scol,
                  (char*)Bl + r * 4096 + wave * 1024);
    }
    __syncthreads();
    bf16x8 af[4], bfr[4];
#pragma unroll
    for (int m = 0; m < 4; ++m)
      af[m] = *(const bf16x8*)&Al[(wr + m * 16 + (lane & 15)) * 32 + ka];
#pragma unroll
    for (int n = 0; n < 4; ++n)
      bfr[n] = *(const bf16x8*)&Bl[(wc + n * 16 + (lane & 15)) * 32 + ka];
#pragma unroll
    for (int m = 0; m < 4; ++m)
#pragma unroll
      for (int n = 0; n < 4; ++n)
        acc[m][n] = __builtin_amdgcn_mfma_f32_16x16x32_bf16(af[m], bfr[n], acc[m][n], 0, 0, 0);
    __syncthreads();
  }

#pragma unroll
  for (int m = 0; m < 4; ++m)
#pragma unroll
    for (int n = 0; n < 4; ++n)
#pragma unroll
      for (int j = 0; j < 4; ++j) {
        int row = m0 + wr + m * 16 + (lane >> 4) * 4 + j;
        int col = n0 + wc + n * 16 + (lane & 15);
        float v = acc[m][n][j] + bias[col];
        if (MODE == 1) {
          outF[(size_t)row * CDIM + col] = v;
        } else {
          int which = col >> 10;
          int h = (col >> 6) & 15;
          int d = col & 63;
          int b = row >> 11, t = row & (T_SEQ - 1);
          int bh = b * NHEAD + h;
          unsigned short bv = f2bf(v);
          if (which == 0)      qb[((size_t)bh * T_SEQ + t) * HS + d] = bv;
          else if (which == 1) kb[((size_t)bh * T_SEQ + t) * HS + d] = bv;
          else                 vb[((size_t)bh * HS + d) * T_SEQ + t] = bv;
        }
      }
}

// Barrier-free flash attention, one wave per 32 q-rows (2048 independent waves).
// K,V fragments read directly from global (L2-resident per XCD after remap).
// kf of the NEXT tile is loaded between QK and softmax (zero-cost pipeline).
// Only P goes through wave-private padded LDS (stride 72 elems -> no conflicts).
// q,k: [bh][t][64] bf16; v: [bh][64][t] bf16 (transposed); y: [4096][1024] bf16.
#define PSTR 72
__global__ __launch_bounds__(64) void k_attn(const unsigned short* __restrict__ qb,
                                             const unsigned short* __restrict__ kb,
                                             const unsigned short* __restrict__ vb,
                                             unsigned short* __restrict__ yb) {
  __shared__ __align__(16) unsigned short Pw[32 * PSTR];
  // rid -> (xcd, bh, q-group). 8 XCDs x 4 bh x 64 groups. Heavy groups first.
  const int rid = blockIdx.x;
  const int xcd = rid & 7, i = rid >> 3;       // i in 0..255
  const int bh = xcd * 4 + (i & 3);
  const int g = 63 - (i >> 2);                 // 63 (heaviest) down to 0
  const int lane = threadIdx.x;
  const int l15 = lane & 15, lh = lane >> 4;
  const int q0w = g * 32;                      // this wave's 32 q-rows
  const unsigned short* qh = qb + (size_t)bh * T_SEQ * HS;
  const unsigned short* kh = kb + (size_t)bh * T_SEQ * HS;
  const unsigned short* vh = vb + (size_t)bh * HS * T_SEQ;

  bf16x8 qf[2][2];
#pragma unroll
  for (int m = 0; m < 2; ++m)
#pragma unroll
    for (int kk = 0; kk < 2; ++kk)
      qf[m][kk] = *(const bf16x8*)&qh[(size_t)(q0w + m * 16 + l15) * HS + kk * 32 + lh * 8];

  f32x4 o[2][4];
  float Mx[2][4], Ls[2][4];
#pragma unroll
  for (int m = 0; m < 2; ++m) {
#pragma unroll
    for (int n = 0; n < 4; ++n) o[m][n] = f32x4{0.f, 0.f, 0.f, 0.f};
#pragma unroll
    for (int j = 0; j < 4; ++j) { Mx[m][j] = -INFINITY; Ls[m][j] = 0.f; }
  }

  const float SC = 0.125f * 1.44269504f;  // 1/sqrt(64) * log2(e)
  const int nkt = (q0w >> 6) + 1;

  bf16x8 kf[4][2], vf[4][2];
  // prologue: K fragments of tile 0
#pragma unroll
  for (int n = 0; n < 4; ++n)
#pragma unroll
    for (int kk = 0; kk < 2; ++kk)
      kf[n][kk] = *(const bf16x8*)&kh[(size_t)(n * 16 + l15) * HS + kk * 32 + lh * 8];

  for (int kt = 0; kt < nkt; ++kt) {
    const int kvb = kt * 64;
    // V fragments for THIS tile (used only after softmax -> latency hidden)
#pragma unroll
    for (int n = 0; n < 4; ++n)
#pragma unroll
      for (int kk = 0; kk < 2; ++kk)
        vf[n][kk] = *(const bf16x8*)&vh[(size_t)(n * 16 + l15) * T_SEQ + kvb + kk * 32 + lh * 8];

    f32x4 s2[2][4];
#pragma unroll
    for (int m = 0; m < 2; ++m)
#pragma unroll
      for (int n = 0; n < 4; ++n) {
        f32x4 z = f32x4{0.f, 0.f, 0.f, 0.f};
        z = __builtin_amdgcn_mfma_f32_16x16x32_bf16(qf[m][0], kf[n][0], z, 0, 0, 0);
        z = __builtin_amdgcn_mfma_f32_16x16x32_bf16(qf[m][1], kf[n][1], z, 0, 0, 0);
        s2[m][n] = z;
      }

    // K fragments for NEXT tile: old kf is dead after the MFMAs above, so this
    // costs no extra registers; its latency hides under softmax + P + PV.
    if (kt + 1 < nkt) {
      const int kvb2 = kvb + 64;
#pragma unroll
      for (int n = 0; n < 4; ++n)
#pragma unroll
        for (int kk = 0; kk < 2; ++kk)
          kf[n][kk] = *(const bf16x8*)&kh[(size_t)(kvb2 + n * 16 + l15) * HS + kk * 32 + lh * 8];
    }

    const bool diag = (kvb + 63 > q0w);
#pragma unroll
    for (int m = 0; m < 2; ++m)
#pragma unroll
      for (int j = 0; j < 4; ++j) {
        const int qg = q0w + m * 16 + lh * 4 + j;
        float sv[4];
        float mx = -3.0e38f;
#pragma unroll
        for (int n = 0; n < 4; ++n) {
          float v = s2[m][n][j] * SC;  // log2-domain scores
          if (diag && (kvb + n * 16 + l15 > qg)) v = -3.0e38f;
          sv[n] = v;
          mx = fmaxf(mx, v);
        }
        mx = fmaxf(mx, __shfl_xor(mx, 1));
        mx = fmaxf(mx, __shfl_xor(mx, 2));
        mx = fmaxf(mx, __shfl_xor(mx, 4));
        mx = fmaxf(mx, __shfl_xor(mx, 8));
        const float newM = fmaxf(Mx[m][j], mx);
        const float alpha = __builtin_exp2f(Mx[m][j] - newM);
        float rs = 0.f;
#pragma unroll
        for (int n = 0; n < 4; ++n) {
          float p = __builtin_exp2f(sv[n] - newM);
          rs += p;
          Pw[(m * 16 + lh * 4 + j) * PSTR + n * 16 + l15] = f2bf(p);
        }
        rs += __shfl_xor(rs, 1);
        rs += __shfl_xor(rs, 2);
        rs += __shfl_xor(rs, 4);
        rs += __shfl_xor(rs, 8);
        Ls[m][j] = Ls[m][j] * alpha + rs;
        Mx[m][j] = newM;
#pragma unroll
        for (int n = 0; n < 4; ++n) o[m][n][j] *= alpha;
      }

    __builtin_amdgcn_wave_barrier();  // keep ds_writes above the reads below

    bf16x8 pf[2][2];
#pragma unroll
    for (int m = 0; m < 2; ++m)
#pragma unroll
      for (int kk = 0; kk < 2; ++kk)
        pf[m][kk] = *(const bf16x8*)&Pw[(m * 16 + l15) * PSTR + kk * 32 + lh * 8];

#pragma unroll
    for (int m = 0; m < 2; ++m)
#pragma unroll
      for (int n = 0; n < 4; ++n) {
        o[m][n] = __builtin_amdgcn_mfma_f32_16x16x32_bf16(pf[m][0], vf[n][0], o[m][n], 0, 0, 0);
        o[m][n] = __builtin_amdgcn_mfma_f32_16x16x32_bf16(pf[m][1], vf[n][1], o[m][n], 0, 0, 0);
      }
  }

  const int b = bh >> 4, h = bh & 15;
#pragma unroll
  for (int m = 0; m < 2; ++m)
#pragma unroll
    for (int j = 0; j < 4; ++j) {
      const float inv = 1.0f / Ls[m][j];
      const int tg = b * T_SEQ + q0w + m * 16 + lh * 4 + j;
#pragma unroll
      for (int n = 0; n < 4; ++n)
        yb[(size_t)tg * CDIM + h * 64 + n * 16 + l15] = f2bf(o[m][n][j] * inv);
    }
}

extern "C" void kernel_launch(void* const* d_in, const int* in_sizes, int n_in,
                              void* d_out, int out_size, void* d_ws, size_t ws_size,
                              hipStream_t stream) {
  (void)in_sizes; (void)n_in; (void)out_size; (void)ws_size;
  const float* x      = (const float*)d_in[0];
  const float* W_attn = (const float*)d_in[1];
  const float* b_attn = (const float*)d_in[2];
  const float* W_proj = (const float*)d_in[3];
  const float* b_proj = (const float*)d_in[4];
  float* out = (float*)d_out;
  char* ws = (char*)d_ws;

  unsigned short* xb  = (unsigned short*)(ws);              //  8 MiB [4096][1024]
  unsigned short* Wta = (unsigned short*)(ws + 8388608);    //  6 MiB [3072][1024]
  unsigned short* Wtp = (unsigned short*)(ws + 14680064);   //  2 MiB [1024][1024]
  unsigned short* qbf = (unsigned short*)(ws + 16777216);   //  8 MiB [32][2048][64]
  unsigned short* kbf = (unsigned short*)(ws + 25165824);   //  8 MiB [32][2048][64]
  unsigned short* vbf = (unsigned short*)(ws + 33554432);   //  8 MiB [32][64][2048]
  unsigned short* ybf = (unsigned short*)(ws + 41943040);   //  8 MiB [4096][1024]

  k_cvt_x<<<4096, 256, 0, stream>>>(x, xb);
  k_transpose<<<dim3(96, 32), 256, 0, stream>>>(W_attn, Wta, 1024, 3072);
  k_transpose<<<dim3(32, 32), 256, 0, stream>>>(W_proj, Wtp, 1024, 1024);
  k_gemm<0, 1024><<<dim3(32, 24), 256, 0, stream>>>(xb, Wta, b_attn, nullptr, qbf, kbf, vbf);
  k_attn<<<2048, 64, 0, stream>>>(qbf, kbf, vbf, ybf);
  k_gemm<1, 1024><<<dim3(32, 8), 256, 0, stream>>>(ybf, Wtp, b_proj, out, nullptr, nullptr, nullptr);
}

// Round 4
// 151.834 us; speedup vs baseline: 1.6142x; 1.2902x over previous
//
#include <hip/hip_runtime.h>
#include <stdint.h>

#define T_SEQ 2048
#define CDIM 1024
#define NHEAD 16
#define HS 64

typedef __bf16 bf16x8 __attribute__((ext_vector_type(8)));
typedef float f32x4 __attribute__((ext_vector_type(4)));

__device__ __forceinline__ unsigned short f2bf(float f) {
  union { float f; unsigned u; } c; c.f = f;
  unsigned r = c.u + 0x7FFFu + ((c.u >> 16) & 1u);
  return (unsigned short)(r >> 16);
}

__device__ __forceinline__ void gload_lds16(const void* g, void* l) {
  __builtin_amdgcn_global_load_lds((__attribute__((address_space(1))) void*)(g),
                                   (__attribute__((address_space(3))) void*)(l),
                                   16, 0, 0);
}

// x fp32 [4096][1024] -> bf16 same layout. 4 elems/thread.
__global__ __launch_bounds__(256) void k_cvt_x(const float* __restrict__ x,
                                               unsigned short* __restrict__ xb) {
  int i = blockIdx.x * 256 + threadIdx.x;
  float4 f = reinterpret_cast<const float4*>(x)[i];
  ushort4 u;
  u.x = f2bf(f.x); u.y = f2bf(f.y); u.z = f2bf(f.z); u.w = f2bf(f.w);
  reinterpret_cast<ushort4*>(xb)[i] = u;
}

// W [K][N] fp32 -> Wt [N][K] bf16 (tiled transpose)
__global__ __launch_bounds__(256) void k_transpose(const float* __restrict__ W,
                                                   unsigned short* __restrict__ Wt,
                                                   int K, int N) {
  __shared__ float tile[32][33];
  int n0 = blockIdx.x * 32, k0 = blockIdx.y * 32;
  int c = threadIdx.x & 31, r0 = threadIdx.x >> 5;
#pragma unroll
  for (int r = r0; r < 32; r += 8) tile[r][c] = W[(size_t)(k0 + r) * N + n0 + c];
  __syncthreads();
#pragma unroll
  for (int r = r0; r < 32; r += 8) Wt[(size_t)(n0 + r) * K + k0 + c] = f2bf(tile[c][r]);
}

// C = A[M][KD] * Bt[N][KD]^T + bias. 128x128 tile, 4 waves, BK=32.
// MODE 0: qkv scatter epilogue (bf16, K pre-scaled by 1/sqrt(hs)*log2e).
// MODE 1: fp32 out.
template <int MODE, int KD>
__global__ __launch_bounds__(256) void k_gemm(const unsigned short* __restrict__ A,
                                              const unsigned short* __restrict__ Bt,
                                              const float* __restrict__ bias,
                                              float* __restrict__ outF,
                                              unsigned short* __restrict__ qb,
                                              unsigned short* __restrict__ kb,
                                              unsigned short* __restrict__ vb) {
  __shared__ __align__(16) unsigned short Al[128 * 32];
  __shared__ __align__(16) unsigned short Bl[128 * 32];
  const int tid = threadIdx.x;
  const int wave = tid >> 6, lane = tid & 63;
  const int m0 = blockIdx.x * 128, n0 = blockIdx.y * 128;
  const int wr = (wave >> 1) * 64, wc = (wave & 1) * 64;
  const int srow = tid >> 2, scol = (tid & 3) * 8;
  const int ka = (lane >> 4) * 8;
  f32x4 acc[4][4];
#pragma unroll
  for (int m = 0; m < 4; ++m)
#pragma unroll
    for (int n = 0; n < 4; ++n) acc[m][n] = f32x4{0.f, 0.f, 0.f, 0.f};

  for (int k0 = 0; k0 < KD; k0 += 32) {
#pragma unroll
    for (int r = 0; r < 2; ++r) {
      gload_lds16(A + (size_t)(m0 + r * 64 + srow) * KD + k0 + scol,
                  (char*)Al + r * 4096 + wave * 1024);
      gload_lds16(Bt + (size_t)(n0 + r * 64 + srow) * KD + k0 + scol,
                  (char*)Bl + r * 4096 + wave * 1024);
    }
    __syncthreads();
    bf16x8 af[4], bfr[4];
#pragma unroll
    for (int m = 0; m < 4; ++m)
      af[m] = *(const bf16x8*)&Al[(wr + m * 16 + (lane & 15)) * 32 + ka];
#pragma unroll
    for (int n = 0; n < 4; ++n)
      bfr[n] = *(const bf16x8*)&Bl[(wc + n * 16 + (lane & 15)) * 32 + ka];
#pragma unroll
    for (int m = 0; m < 4; ++m)
#pragma unroll
      for (int n = 0; n < 4; ++n)
        acc[m][n] = __builtin_amdgcn_mfma_f32_16x16x32_bf16(af[m], bfr[n], acc[m][n], 0, 0, 0);
    __syncthreads();
  }

#pragma unroll
  for (int m = 0; m < 4; ++m)
#pragma unroll
    for (int n = 0; n < 4; ++n)
#pragma unroll
      for (int j = 0; j < 4; ++j) {
        int row = m0 + wr + m * 16 + (lane >> 4) * 4 + j;
        int col = n0 + wc + n * 16 + (lane & 15);
        float v = acc[m][n][j] + bias[col];
        if (MODE == 1) {
          outF[(size_t)row * CDIM + col] = v;
        } else {
          int which = col >> 10;
          int h = (col >> 6) & 15;
          int d = col & 63;
          int b = row >> 11, t = row & (T_SEQ - 1);
          int bh = b * NHEAD + h;
          // Fold attention scale (1/sqrt(64) * log2e) into K.
          unsigned short bv = f2bf(which == 1 ? v * 0.18033688f : v);
          if (which == 0)      qb[((size_t)bh * T_SEQ + t) * HS + d] = bv;
          else if (which == 1) kb[((size_t)bh * T_SEQ + t) * HS + d] = bv;
          else                 vb[((size_t)bh * HS + d) * T_SEQ + t] = bv;
        }
      }
}

// Barrier-free flash attention, one wave per 32 q-rows (2048 independent waves).
// SWAPPED QK^T: computes mfma(K,Q) so each lane holds 16 k-values of ONE q-row
// in registers -> softmax is in-register trees + 2 shfls (vs 8x 4-deep ladders).
// K pre-scaled by 1/sqrt(hs)*log2e in GEMM1 epilogue -> scores already log2-domain.
// K,V fragments read directly from global (L2-resident per XCD after remap).
// Only P goes through wave-private padded LDS (stride 72 elems -> no conflicts).
// q,k: [bh][t][64] bf16; v: [bh][64][t] bf16 (transposed); y: [4096][1024] bf16.
#define PSTR 72
__global__ __launch_bounds__(64) void k_attn(const unsigned short* __restrict__ qb,
                                             const unsigned short* __restrict__ kb,
                                             const unsigned short* __restrict__ vb,
                                             unsigned short* __restrict__ yb) {
  __shared__ __align__(16) unsigned short Pw[32 * PSTR];
  // rid -> (xcd, bh, q-group). 8 XCDs x 4 bh x 64 groups. Heavy groups first.
  const int rid = blockIdx.x;
  const int xcd = rid & 7, i = rid >> 3;       // i in 0..255
  const int bh = xcd * 4 + (i & 3);
  const int g = 63 - (i >> 2);                 // 63 (heaviest) down to 0
  const int lane = threadIdx.x;
  const int l15 = lane & 15, lh = lane >> 4;
  const int q0w = g * 32;                      // this wave's 32 q-rows
  const unsigned short* qh = qb + (size_t)bh * T_SEQ * HS;
  const unsigned short* kh = kb + (size_t)bh * T_SEQ * HS;
  const unsigned short* vh = vb + (size_t)bh * HS * T_SEQ;

  bf16x8 qf[2][2];
#pragma unroll
  for (int m = 0; m < 2; ++m)
#pragma unroll
    for (int kk = 0; kk < 2; ++kk)
      qf[m][kk] = *(const bf16x8*)&qh[(size_t)(q0w + m * 16 + l15) * HS + kk * 32 + lh * 8];

  f32x4 o[2][4];                 // PV layout: q = m*16 + lh*4 + j, d = n*16 + l15
  float Mx[2], Ls[2];            // softmax layout: q = np*16 + l15 (per lane)
#pragma unroll
  for (int m = 0; m < 2; ++m) {
#pragma unroll
    for (int n = 0; n < 4; ++n) o[m][n] = f32x4{0.f, 0.f, 0.f, 0.f};
    Mx[m] = -INFINITY; Ls[m] = 0.f;
  }

  const int nkt = (q0w >> 6) + 1;

  bf16x8 kf[4][2], vf[4][2];
  // prologue: K fragments of tile 0
#pragma unroll
  for (int n = 0; n < 4; ++n)
#pragma unroll
    for (int kk = 0; kk < 2; ++kk)
      kf[n][kk] = *(const bf16x8*)&kh[(size_t)(n * 16 + l15) * HS + kk * 32 + lh * 8];

  for (int kt = 0; kt < nkt; ++kt) {
    const int kvb = kt * 64;
    // V fragments for THIS tile (used only after softmax -> latency hidden)
#pragma unroll
    for (int n = 0; n < 4; ++n)
#pragma unroll
      for (int kk = 0; kk < 2; ++kk)
        vf[n][kk] = *(const bf16x8*)&vh[(size_t)(n * 16 + l15) * T_SEQ + kvb + kk * 32 + lh * 8];

    // Swapped QK^T: s2[np][mp] = S^T block, q = np*16+l15, k = kvb+mp*16+lh*4+j
    f32x4 s2[2][4];
#pragma unroll
    for (int np = 0; np < 2; ++np)
#pragma unroll
      for (int mp = 0; mp < 4; ++mp) {
        f32x4 z = f32x4{0.f, 0.f, 0.f, 0.f};
        z = __builtin_amdgcn_mfma_f32_16x16x32_bf16(kf[mp][0], qf[np][0], z, 0, 0, 0);
        z = __builtin_amdgcn_mfma_f32_16x16x32_bf16(kf[mp][1], qf[np][1], z, 0, 0, 0);
        s2[np][mp] = z;
      }

    // K fragments for NEXT tile: old kf dead after the MFMAs above.
    if (kt + 1 < nkt) {
      const int kvb2 = kvb + 64;
#pragma unroll
      for (int n = 0; n < 4; ++n)
#pragma unroll
        for (int kk = 0; kk < 2; ++kk)
          kf[n][kk] = *(const bf16x8*)&kh[(size_t)(kvb2 + n * 16 + l15) * HS + kk * 32 + lh * 8];
    }

    const bool diag = (kvb + 63 > q0w);
    float alpha_sm[2];
#pragma unroll
    for (int np = 0; np < 2; ++np) {
      const int qg = q0w + np * 16 + l15;
      if (diag) {
#pragma unroll
        for (int mp = 0; mp < 4; ++mp)
#pragma unroll
          for (int j = 0; j < 4; ++j)
            if (kvb + mp * 16 + lh * 4 + j > qg) s2[np][mp][j] = -3.0e38f;
      }
      // in-register row max (full ILP) + 2-shfl cross-quadrant reduce
      f32x4 t01, t23, t;
#pragma unroll
      for (int e = 0; e < 4; ++e) {
        t01[e] = fmaxf(s2[np][0][e], s2[np][1][e]);
        t23[e] = fmaxf(s2[np][2][e], s2[np][3][e]);
        t[e] = fmaxf(t01[e], t23[e]);
      }
      float mx = fmaxf(fmaxf(t[0], t[1]), fmaxf(t[2], t[3]));
      mx = fmaxf(mx, __shfl_xor(mx, 16));
      mx = fmaxf(mx, __shfl_xor(mx, 32));
      const float newM = fmaxf(Mx[np], mx);
      alpha_sm[np] = __builtin_exp2f(Mx[np] - newM);
      Mx[np] = newM;
      float rs = 0.f;
      uint2 w[4];
#pragma unroll
      for (int mp = 0; mp < 4; ++mp) {
        float p0 = __builtin_exp2f(s2[np][mp][0] - newM);
        float p1 = __builtin_exp2f(s2[np][mp][1] - newM);
        float p2 = __builtin_exp2f(s2[np][mp][2] - newM);
        float p3 = __builtin_exp2f(s2[np][mp][3] - newM);
        rs += (p0 + p1) + (p2 + p3);
        unsigned lo, hi;
        asm("v_cvt_pk_bf16_f32 %0, %1, %2" : "=v"(lo) : "v"(p0), "v"(p1));
        asm("v_cvt_pk_bf16_f32 %0, %1, %2" : "=v"(hi) : "v"(p2), "v"(p3));
        w[mp].x = lo; w[mp].y = hi;
      }
      rs += __shfl_xor(rs, 16);
      rs += __shfl_xor(rs, 32);
      Ls[np] = Ls[np] * alpha_sm[np] + rs;
#pragma unroll
      for (int mp = 0; mp < 4; ++mp)
        *(uint2*)&Pw[(np * 16 + l15) * PSTR + mp * 16 + lh * 4] = w[mp];
    }

    // broadcast alpha to PV layout (1-deep bpermutes) and rescale o
#pragma unroll
    for (int m = 0; m < 2; ++m)
#pragma unroll
      for (int j = 0; j < 4; ++j) {
        const float a = __shfl(alpha_sm[m], lh * 4 + j, 16);
#pragma unroll
        for (int n = 0; n < 4; ++n) o[m][n][j] *= a;
      }

    __builtin_amdgcn_wave_barrier();  // keep ds_writes above the reads below

    bf16x8 pf[2][2];
#pragma unroll
    for (int m = 0; m < 2; ++m)
#pragma unroll
      for (int kk = 0; kk < 2; ++kk)
        pf[m][kk] = *(const bf16x8*)&Pw[(m * 16 + l15) * PSTR + kk * 32 + lh * 8];

#pragma unroll
    for (int m = 0; m < 2; ++m)
#pragma unroll
      for (int n = 0; n < 4; ++n) {
        o[m][n] = __builtin_amdgcn_mfma_f32_16x16x32_bf16(pf[m][0], vf[n][0], o[m][n], 0, 0, 0);
        o[m][n] = __builtin_amdgcn_mfma_f32_16x16x32_bf16(pf[m][1], vf[n][1], o[m][n], 0, 0, 0);
      }
  }

  const int b = bh >> 4, h = bh & 15;
  float inv_sm[2] = {1.0f / Ls[0], 1.0f / Ls[1]};
#pragma unroll
  for (int m = 0; m < 2; ++m)
#pragma unroll
    for (int j = 0; j < 4; ++j) {
      const float inv = __shfl(inv_sm[m], lh * 4 + j, 16);
      const int tg = b * T_SEQ + q0w + m * 16 + lh * 4 + j;
#pragma unroll
      for (int n = 0; n < 4; ++n)
        yb[(size_t)tg * CDIM + h * 64 + n * 16 + l15] = f2bf(o[m][n][j] * inv);
    }
}

extern "C" void kernel_launch(void* const* d_in, const int* in_sizes, int n_in,
                              void* d_out, int out_size, void* d_ws, size_t ws_size,
                              hipStream_t stream) {
  (void)in_sizes; (void)n_in; (void)out_size; (void)ws_size;
  const float* x      = (const float*)d_in[0];
  const float* W_attn = (const float*)d_in[1];
  const float* b_attn = (const float*)d_in[2];
  const float* W_proj = (const float*)d_in[3];
  const float* b_proj = (const float*)d_in[4];
  float* out = (float*)d_out;
  char* ws = (char*)d_ws;

  unsigned short* xb  = (unsigned short*)(ws);              //  8 MiB [4096][1024]
  unsigned short* Wta = (unsigned short*)(ws + 8388608);    //  6 MiB [3072][1024]
  unsigned short* Wtp = (unsigned short*)(ws + 14680064);   //  2 MiB [1024][1024]
  unsigned short* qbf = (unsigned short*)(ws + 16777216);   //  8 MiB [32][2048][64]
  unsigned short* kbf = (unsigned short*)(ws + 25165824);   //  8 MiB [32][2048][64]
  unsigned short* vbf = (unsigned short*)(ws + 33554432);   //  8 MiB [32][64][2048]
  unsigned short* ybf = (unsigned short*)(ws + 41943040);   //  8 MiB [4096][1024]

  k_cvt_x<<<4096, 256, 0, stream>>>(x, xb);
  k_transpose<<<dim3(96, 32), 256, 0, stream>>>(W_attn, Wta, 1024, 3072);
  k_transpose<<<dim3(32, 32), 256, 0, stream>>>(W_proj, Wtp, 1024, 1024);
  k_gemm<0, 1024><<<dim3(32, 24), 256, 0, stream>>>(xb, Wta, b_attn, nullptr, qbf, kbf, vbf);
  k_attn<<<2048, 64, 0, stream>>>(qbf, kbf, vbf, ybf);
  k_gemm<1, 1024><<<dim3(32, 8), 256, 0, stream>>>(ybf, Wtp, b_proj, out, nullptr, nullptr, nullptr);
}